// Round 1
// baseline (445.855 us; speedup 1.0000x reference)
//
#include <hip/hip_runtime.h>
#include <hip/hip_bf16.h>
#include <stdint.h>

#define E_DIM 768
#define S_LEN 2048
#define BATCH 8

typedef __attribute__((ext_vector_type(8))) short short8;   // 8 x bf16 = 4 VGPRs
typedef __attribute__((ext_vector_type(4))) float floatx4;  // MFMA C/D

__device__ __forceinline__ short f2bf(float f) {
    return __builtin_bit_cast(short, __float2bfloat16(f));
}

__device__ __forceinline__ floatx4 mfma16(short8 a, short8 b, floatx4 c) {
    return __builtin_amdgcn_mfma_f32_16x16x32_bf16(a, b, c, 0, 0, 0);
}

// async global->LDS, 16B per lane; LDS dst is wave-uniform base + lane*16,
// global src per-lane free -> swizzle realized by permuting the SOURCE.
__device__ __forceinline__ void glds16(const short* g, short* l) {
    __builtin_amdgcn_global_load_lds(
        (const __attribute__((address_space(1))) void*)g,
        (__attribute__((address_space(3))) void*)l,
        16, 0, 0);
}

// ---------------------------------------------------------------------------
// Shared GEMM core v2: C[256x256] += A[256xK] * B[256xK]^T, row strides sA/sB.
// 512 threads = 8 waves (2m x 4n), per-wave 128x64 via 8x4 frags of 16x16x32.
//
// R5 redesign (T3+T4+T5 from the technique catalog): the old core was the
// 2-barrier-per-K64 structure -- vmcnt(0)+lgkmcnt(0) drain at every
// __syncthreads stalled all waves together (proj: MfmaUtil 24.6%, VALUBusy
// 12%, HBM 19.6%, conflicts 0 -> structure/latency-bound, not pipe-bound).
// New structure: BK=32, ring-4 LDS (128KB), stage 3 K-tiles AHEAD with
// global_load_lds, counted s_waitcnt vmcnt(8) (never drains in steady
// state), ONE raw s_barrier per K-tile, setprio(1) around the MFMA cluster.
// Ring-4 invariant: iter t holds tiles {t..t+3} in slots t&3..(t+3)&3 --
// the staging target (t+3)&3 re-uses the buffer whose reads all completed
// before the previous barrier => race-free with a single barrier.
//
// LDS swizzle (BK=32 -> 4 x 16B units/row): unit u of row r lives at slot
// u ^ ((r>>1)&3).  Frag read (lane: r=base+(l&15), u=l>>4) then hits granule
// (r&1)*4 + (u ^ ((l&15)>>1)&3): exactly 8 lanes per 16B granule -> even,
// conflict-free ds_read_b128 (predicted SQ_LDS_BANK_CONFLICT ~ 0).
// Staging: lane l writes linear slot l&3 of row srw+(l>>2); source unit
// u = (l&3) ^ ((l>>3)&3) pre-permuted on the GLOBAL address.
// Requires K >= 128 (always true here: K=768 or nvp>=128).
// ---------------------------------------------------------------------------
__device__ __forceinline__ void gemm_core(
    const short* __restrict__ Ab, size_t sA,
    const short* __restrict__ Bb, size_t sB,
    int K, short* At, short* Bt,
    floatx4 acc[8][4])
{
    const int tid  = threadIdx.x;
    const int lane = tid & 63;
    const int wv   = tid >> 6;
    const int lm   = lane & 15, lq = lane >> 4;
    const int wm   = (wv >> 2) << 7;            // 0 / 128
    const int wn   = (wv & 3) << 6;             // 0 / 64 / 128 / 192
    const int fsw  = lq ^ ((lm >> 1) & 3);      // read-side swizzle (lane-const)
    const int nt   = K >> 5;                    // K-tiles of 32

    // staging geometry: wave wv covers rows [wv*16, wv*16+16) per 128-row half
    const int su   = (lane & 3) ^ ((lane >> 3) & 3);   // source unit (swizzled)
    const int srw  = (wv << 4) + (lane >> 2);          // source row in half
    const short* aS0 = Ab + (size_t)srw * sA + su * 8;
    const short* aS1 = aS0 + (size_t)128 * sA;
    const short* bS0 = Bb + (size_t)srw * sB + su * 8;
    const short* bS1 = bS0 + (size_t)128 * sB;
    short* Alw = At + (wv << 9);               // wave-uniform LDS base
    short* Blw = Bt + (wv << 9);

#define STAGE(tt) {                                   \
        const int b4 = ((tt) & 3) << 13;              \
        const int kc = (tt) << 5;                     \
        glds16(aS0 + kc, Alw + b4);                   \
        glds16(bS0 + kc, Blw + b4);                   \
        glds16(aS1 + kc, Alw + b4 + 4096);            \
        glds16(bS1 + kc, Blw + b4 + 4096); }

    // prologue: 3 tiles in flight (12 loads); vmcnt(8) -> tile 0 landed
    STAGE(0) STAGE(1) STAGE(2)
    asm volatile("s_waitcnt vmcnt(8)" ::: "memory");
    __builtin_amdgcn_s_barrier();

    for (int t = 0; t < nt; ++t) {
        if (t + 3 < nt) STAGE(t + 3)

        const short* ab = At + ((t & 3) << 13);
        const short* bb = Bt + ((t & 3) << 13);
        short8 af[8], bf[4];
#pragma unroll
        for (int i = 0; i < 8; ++i)
            af[i] = *(const short8*)&ab[((wm + i * 16 + lm) * 4 + fsw) * 8];
#pragma unroll
        for (int j = 0; j < 4; ++j)
            bf[j] = *(const short8*)&bb[((wn + j * 16 + lm) * 4 + fsw) * 8];

        __builtin_amdgcn_s_setprio(1);
#pragma unroll
        for (int i = 0; i < 8; ++i)
#pragma unroll
            for (int j = 0; j < 4; ++j)
                acc[i][j] = mfma16(af[i], bf[j], acc[i][j]);
        __builtin_amdgcn_s_setprio(0);

        // counted waits: in-flight after staging = tiles t+1..min(t+3,nt-1);
        // need tile t+1 landed before next iter's reads.
        const int rem = nt - 1 - t;
        if (rem >= 3)      asm volatile("s_waitcnt vmcnt(8)" ::: "memory");
        else if (rem == 2) asm volatile("s_waitcnt vmcnt(4)" ::: "memory");
        else if (rem == 1) asm volatile("s_waitcnt vmcnt(0)" ::: "memory");
        if (rem > 0) __builtin_amdgcn_s_barrier();
    }
#undef STAGE
}

// ---------------------------------------------------------------------------
// prep: fused front-end (unchanged from R4).
// ---------------------------------------------------------------------------
__global__ void prep(const float* __restrict__ Wv, const float* __restrict__ Wk,
                     const float* __restrict__ Wq, const float* __restrict__ Wo,
                     const float* __restrict__ query, const int* __restrict__ mask,
                     short* __restrict__ Wb, short* __restrict__ xq,
                     float* __restrict__ rowsum,
                     int* __restrict__ jidx, int* __restrict__ nv,
                     int* __restrict__ nvp)
{
    __shared__ int cnt[256];
    const int blk = blockIdx.x;
    const int t   = threadIdx.x;

    if (blk < 2304) {                       // ---- weight convert
        const int z = blk / 576;
        const float* src = (z == 0) ? Wv : (z == 1) ? Wk : (z == 2) ? Wq : Wo;
        const float scale = (z == 2) ? (1.0f / (float)E_DIM) : 1.0f;
        size_t i = ((size_t)(blk - z * 576) * 256 + t) * 4;
        float4 f = *(const float4*)(src + i);
        short4 h;
        h.x = f2bf(f.x * scale); h.y = f2bf(f.y * scale);
        h.z = f2bf(f.z * scale); h.w = f2bf(f.w * scale);
        *(short4*)(Wb + (size_t)z * E_DIM * E_DIM + i) = h;
    } else if (blk < 6400) {                // ---- query convert, 4 rows/block
        const int g0 = blk - 2304;
        const size_t base = (size_t)g0 * 4 * E_DIM;
#pragma unroll
        for (int p = 0; p < 3; ++p) {
            size_t i = base + ((size_t)p * 256 + t) * 4;
            float4 f = *(const float4*)(query + i);
            short4 h;
            h.x = f2bf(f.x); h.y = f2bf(f.y); h.z = f2bf(f.z); h.w = f2bf(f.w);
            *(short4*)(xq + i) = h;
        }
    } else if (blk < 6416) {                // ---- rowsum zero
        const int g0 = blk - 6400;
        *(float4*)(rowsum + ((size_t)g0 * 256 + t) * 4) = (float4){0.f, 0.f, 0.f, 0.f};
    } else {                                // ---- mask compaction
        const int b = blk - 6416;
        int m[8];
        int c = 0;
#pragma unroll
        for (int k = 0; k < 8; ++k) {
            m[k] = mask[b * S_LEN + t * 8 + k];
            c += (m[k] != 0);
        }
        cnt[t] = c;
        __syncthreads();
        for (int off = 1; off < 256; off <<= 1) {
            int v = (t >= off) ? cnt[t - off] : 0;
            __syncthreads();
            cnt[t] += v;
            __syncthreads();
        }
        int pos = cnt[t] - c;
        const int total = cnt[255];
#pragma unroll
        for (int k = 0; k < 8; ++k)
            if (m[k] != 0) jidx[b * S_LEN + (pos++)] = t * 8 + k;
        __syncthreads();
        for (int i = total + t; i < S_LEN; i += 256) jidx[b * S_LEN + i] = 0;
        if (t == 0) {
            nv[b] = total;
            int p = (total + 127) & ~127;
            if (p < 128) p = 128;
            nvp[b] = p;
        }
    }
}

// ---------------------------------------------------------------------------
// gather+convert value/key rows through jidx (compacted). 4 rows/block.
// ---------------------------------------------------------------------------
__global__ void gather_vk(const float* __restrict__ v, const float* __restrict__ k,
                          const int* __restrict__ jidx, const int* __restrict__ nvp,
                          short* __restrict__ xv, short* __restrict__ xk) {
    const int z = blockIdx.y, b = blockIdx.z;
    const int r0 = blockIdx.x * 4;
    if (r0 >= nvp[b]) return;
    const float* src = (z == 0) ? v : k;
    short* dst = (z == 0) ? xv : xk;
    const int tid = threadIdx.x;
#pragma unroll
    for (int p = 0; p < 3; ++p) {
        int g   = p * 256 + tid;
        int row = r0 + g / 192;
        int c4  = (g % 192) * 4;
        int srow = jidx[b * S_LEN + row];
        float4 f = *(const float4*)(src + ((size_t)b * S_LEN + srow) * E_DIM + c4);
        short4 h;
        h.x = f2bf(f.x); h.y = f2bf(f.y); h.z = f2bf(f.z); h.w = f2bf(f.w);
        *(short4*)(dst + ((size_t)b * S_LEN + row) * E_DIM + c4) = h;
    }
}

// ---------------------------------------------------------------------------
// Projections: 256x256 tiles. z==0: V -> vt[b][n][i] (transposed);
// z==1: K compacted -> kb[b][i][e]; z==2: Q -> qb[m][e].
// grid (64, 3, 3): mt covers 64 m-tiles (z=2: 16384 rows; z<2: 8/batch).
// ---------------------------------------------------------------------------
__global__ __launch_bounds__(512, 2) void proj_kernel(
    const short* __restrict__ xv, const short* __restrict__ xk, const short* __restrict__ xq,
    const short* __restrict__ Wb, const int* __restrict__ nvp,
    short* __restrict__ vt, short* __restrict__ kb, short* __restrict__ qb)
{
    const int z  = blockIdx.z;
    const int mt = blockIdx.x;
    const int n0 = blockIdx.y * 256;

    int b = 0, lm0 = 0;
    const short* X;
    if (z == 2) {
        X = xq + (size_t)mt * 256 * E_DIM;
    } else {
        b   = mt >> 3;
        lm0 = (mt & 7) * 256;
        if (lm0 >= nvp[b]) return;
        X = ((z == 0) ? xv : xk) + ((size_t)b * S_LEN + lm0) * E_DIM;
    }
    const short* W = Wb + (size_t)z * E_DIM * E_DIM + (size_t)n0 * E_DIM;

    __shared__ __align__(16) short At[4 * 8192];
    __shared__ __align__(16) short Bt[4 * 8192];

    floatx4 acc[8][4];
#pragma unroll
    for (int i = 0; i < 8; ++i)
#pragma unroll
        for (int j = 0; j < 4; ++j) acc[i][j] = (floatx4){0.f, 0.f, 0.f, 0.f};

    gemm_core(X, E_DIM, W, E_DIM, E_DIM, At, Bt, acc);

    const int lane = threadIdx.x & 63, wv = threadIdx.x >> 6;
    const int lm = lane & 15, lq = lane >> 4;
    const int wm = (wv >> 2) << 7, wn = (wv & 3) << 6;

    if (z == 0) {        // vt[b][n][i]
#pragma unroll
        for (int i = 0; i < 8; ++i)
#pragma unroll
            for (int r = 0; r < 4; ++r) {
                int li = lm0 + wm + i * 16 + lq * 4 + r;
#pragma unroll
                for (int j = 0; j < 4; ++j) {
                    int n = n0 + wn + j * 16 + lm;
                    vt[((size_t)b * E_DIM + n) * S_LEN + li] = f2bf(acc[i][j][r]);
                }
            }
    } else if (z == 1) { // kb[b][i][e]
#pragma unroll
        for (int i = 0; i < 8; ++i)
#pragma unroll
            for (int r = 0; r < 4; ++r) {
                int li = lm0 + wm + i * 16 + lq * 4 + r;
#pragma unroll
                for (int j = 0; j < 4; ++j) {
                    int n = n0 + wn + j * 16 + lm;
                    kb[((size_t)b * S_LEN + li) * E_DIM + n] = f2bf(acc[i][j][r]);
                }
            }
    } else {             // qb[m][e]
#pragma unroll
        for (int i = 0; i < 8; ++i)
#pragma unroll
            for (int r = 0; r < 4; ++r) {
                int m = mt * 256 + wm + i * 16 + lq * 4 + r;
#pragma unroll
                for (int j = 0; j < 4; ++j) {
                    int n = n0 + wn + j * 16 + lm;
                    qb[(size_t)m * E_DIM + n] = f2bf(acc[i][j][r]);
                }
            }
    }
}

// ---------------------------------------------------------------------------
// S = q.k^T over compacted columns; fused exp (no max: |s|<0.5) + rowsum.
// grid (8, 8, 8) = (m-tile, n-tile, batch), skip n0 >= nvp.
// ---------------------------------------------------------------------------
__global__ __launch_bounds__(512, 2) void score_kernel(
    const short* __restrict__ qb, const short* __restrict__ kb,
    const int* __restrict__ nv, const int* __restrict__ nvp,
    short* __restrict__ P, float* __restrict__ rowsum)
{
    const int b  = blockIdx.z;
    const int m0 = blockIdx.x * 256;
    const int n0 = blockIdx.y * 256;
    if (n0 >= nvp[b]) return;

    __shared__ __align__(16) short At[4 * 8192];
    __shared__ __align__(16) short Bt[4 * 8192];

    floatx4 acc[8][4];
#pragma unroll
    for (int i = 0; i < 8; ++i)
#pragma unroll
        for (int j = 0; j < 4; ++j) acc[i][j] = (floatx4){0.f, 0.f, 0.f, 0.f};

    gemm_core(qb + ((size_t)b * S_LEN + m0) * E_DIM, E_DIM,
              kb + ((size_t)b * S_LEN + n0) * E_DIM, E_DIM, E_DIM, At, Bt, acc);

    const int lane = threadIdx.x & 63, wv = threadIdx.x >> 6;
    const int lm = lane & 15, lq = lane >> 4;
    const int wm = (wv >> 2) << 7, wn = (wv & 3) << 6;
    const int nvb = nv[b];

    float rsum[8][4];
#pragma unroll
    for (int i = 0; i < 8; ++i)
#pragma unroll
        for (int r = 0; r < 4; ++r) rsum[i][r] = 0.f;

    const size_t Pbb = (size_t)b * S_LEN * S_LEN;
#pragma unroll
    for (int j = 0; j < 4; ++j) {
        int n = n0 + wn + j * 16 + lm;
        bool valid = n < nvb;
#pragma unroll
        for (int i = 0; i < 8; ++i) {
            int mbase = m0 + wm + i * 16 + lq * 4;
#pragma unroll
            for (int r = 0; r < 4; ++r) {
                float p = valid ? __expf(acc[i][j][r]) : 0.0f;
                rsum[i][r] += p;
                P[Pbb + (size_t)(mbase + r) * S_LEN + n] = f2bf(p);
            }
        }
    }
#pragma unroll
    for (int i = 0; i < 8; ++i)
#pragma unroll
        for (int r = 0; r < 4; ++r) {
            float v = rsum[i][r];
            v += __shfl_xor(v, 1);
            v += __shfl_xor(v, 2);
            v += __shfl_xor(v, 4);
            v += __shfl_xor(v, 8);
            if (lm == 0)
                atomicAdd(&rowsum[b * S_LEN + m0 + wm + i * 16 + lq * 4 + r], v);
        }
}

// ---------------------------------------------------------------------------
// O = (P.V)/rowsum over compacted K (nvp[b]) -> abuf bf16. grid (8, 3, 8).
// ---------------------------------------------------------------------------
__global__ __launch_bounds__(512, 2) void pv_kernel(
    const short* __restrict__ P, const short* __restrict__ vt,
    const float* __restrict__ rowsum, const int* __restrict__ nvp,
    short* __restrict__ abuf)
{
    const int b  = blockIdx.z;
    const int m0 = blockIdx.x * 256;
    const int n0 = blockIdx.y * 256;

    __shared__ __align__(16) short At[4 * 8192];
    __shared__ __align__(16) short Bt[4 * 8192];

    floatx4 acc[8][4];
#pragma unroll
    for (int i = 0; i < 8; ++i)
#pragma unroll
        for (int j = 0; j < 4; ++j) acc[i][j] = (floatx4){0.f, 0.f, 0.f, 0.f};

    gemm_core(P + (size_t)b * S_LEN * S_LEN + (size_t)m0 * S_LEN, S_LEN,
              vt + ((size_t)b * E_DIM + n0) * S_LEN, S_LEN, nvp[b], At, Bt, acc);

    const int lane = threadIdx.x & 63, wv = threadIdx.x >> 6;
    const int lm = lane & 15, lq = lane >> 4;
    const int wm = (wv >> 2) << 7, wn = (wv & 3) << 6;

#pragma unroll
    for (int i = 0; i < 8; ++i) {
        int mbase = m0 + wm + i * 16 + lq * 4;
#pragma unroll
        for (int r = 0; r < 4; ++r) {
            float inv = 1.0f / rowsum[b * S_LEN + mbase + r];
            size_t ob = ((size_t)b * S_LEN + mbase + r) * E_DIM;
#pragma unroll
            for (int j = 0; j < 4; ++j) {
                int n = n0 + wn + j * 16 + lm;
                abuf[ob + n] = f2bf(acc[i][j][r] * inv);
            }
        }
    }
}

// ---------------------------------------------------------------------------
// out[m,n] = A[m,:].Wo[n,:] + bo[n]  (fp32 out). grid (64, 3).
// ---------------------------------------------------------------------------
__global__ __launch_bounds__(512, 2) void out_kernel(
    const short* __restrict__ A, const short* __restrict__ W,
    const float* __restrict__ bias, float* __restrict__ Y)
{
    const int m0 = blockIdx.x * 256;
    const int n0 = blockIdx.y * 256;

    __shared__ __align__(16) short At[4 * 8192];
    __shared__ __align__(16) short Bt[4 * 8192];

    floatx4 acc[8][4];
#pragma unroll
    for (int i = 0; i < 8; ++i)
#pragma unroll
        for (int j = 0; j < 4; ++j) acc[i][j] = (floatx4){0.f, 0.f, 0.f, 0.f};

    gemm_core(A + (size_t)m0 * E_DIM, E_DIM, W + (size_t)n0 * E_DIM, E_DIM,
              E_DIM, At, Bt, acc);

    const int lane = threadIdx.x & 63, wv = threadIdx.x >> 6;
    const int lm = lane & 15, lq = lane >> 4;
    const int wm = (wv >> 2) << 7, wn = (wv & 3) << 6;

#pragma unroll
    for (int j = 0; j < 4; ++j) {
        int n = n0 + wn + j * 16 + lm;
        float bv = bias[n];
#pragma unroll
        for (int i = 0; i < 8; ++i)
#pragma unroll
            for (int r = 0; r < 4; ++r) {
                int m = m0 + wm + i * 16 + lq * 4 + r;
                Y[(size_t)m * E_DIM + n] = acc[i][j][r] + bv;
            }
    }
}

// ---------------------------------------------------------------------------
extern "C" void kernel_launch(void* const* d_in, const int* in_sizes, int n_in,
                              void* d_out, int out_size, void* d_ws, size_t ws_size,
                              hipStream_t stream) {
    const float* value = (const float*)d_in[0];
    const float* key   = (const float*)d_in[1];
    const float* query = (const float*)d_in[2];
    const int*   mask  = (const int*)d_in[3];
    const float* Wv    = (const float*)d_in[4];
    const float* Wk    = (const float*)d_in[5];
    const float* Wq    = (const float*)d_in[6];
    const float* Wo    = (const float*)d_in[7];
    const float* bo    = (const float*)d_in[8];
    float* out = (float*)d_out;

    const size_t WN  = (size_t)E_DIM * E_DIM;
    const size_t ACT = (size_t)BATCH * S_LEN * E_DIM;

    short* Wb  = (short*)d_ws;
    short* xv  = Wb + 4 * WN;
    short* xk  = xv + ACT;
    short* xq  = xk + ACT;
    short* vt  = xq + ACT;
    short* kb  = vt + ACT;
    short* qb  = kb + ACT;
    float* rowsum = (float*)(qb + ACT);
    int*   nv  = (int*)(rowsum + (size_t)BATCH * S_LEN);
    int*   nvp = nv + BATCH;
    int*   jidx = (int*)qb;            // consumed by gather before proj writes qb
    short* P    = xv;                  // overlays dead xv/xk
    short* abuf = qb;                  // overlays dead qb

    prep<<<6424, 256, 0, stream>>>(Wv, Wk, Wq, Wo, query, mask,
                                   Wb, xq, rowsum, jidx, nv, nvp);

    gather_vk<<<dim3(512, 2, 8), 256, 0, stream>>>(value, key, jidx, nvp, xv, xk);

    proj_kernel<<<dim3(64, 3, 3), 512, 0, stream>>>(xv, xk, xq, Wb, nvp,
                                                    vt, kb, qb);

    score_kernel<<<dim3(8, 8, 8), 512, 0, stream>>>(qb, kb, nv, nvp, P, rowsum);

    pv_kernel<<<dim3(8, 3, 8), 512, 0, stream>>>(P, vt, rowsum, nvp, abuf);

    out_kernel<<<dim3(64, 3), 512, 0, stream>>>(abuf, Wb + 3 * WN, bo, out);
}

// Round 2
// 351.275 us; speedup vs baseline: 1.2692x; 1.2692x over previous
//
#include <hip/hip_runtime.h>
#include <hip/hip_bf16.h>
#include <stdint.h>

#define E_DIM 768
#define S_LEN 2048
#define BATCH 8

typedef __attribute__((ext_vector_type(8))) short short8;   // 8 x bf16 = 4 VGPRs
typedef __attribute__((ext_vector_type(4))) float floatx4;  // MFMA C/D

__device__ __forceinline__ short f2bf(float f) {
    return __builtin_bit_cast(short, __float2bfloat16(f));
}

__device__ __forceinline__ floatx4 mfma16(short8 a, short8 b, floatx4 c) {
    return __builtin_amdgcn_mfma_f32_16x16x32_bf16(a, b, c, 0, 0, 0);
}

// async global->LDS, 16B per lane; LDS dst is wave-uniform base + lane*16,
// global src per-lane free -> XOR swizzle realized by permuting the SOURCE.
__device__ __forceinline__ void glds16(const short* g, short* l) {
    __builtin_amdgcn_global_load_lds(
        (const __attribute__((address_space(1))) void*)g,
        (__attribute__((address_space(3))) void*)l,
        16, 0, 0);
}

// ---------------------------------------------------------------------------
// Shared GEMM core: C[128x128] += A[128xK] * B[128xK]^T, row strides sA/sB.
// 256 threads = 4 waves (2x2), each wave 64x64 via 4x4 frags of 16x16x32.
// BK=64 single-buffered; XOR-swizzled staging -> conflict-free ds_read_b128
// (verified R2/R3: SQ_LDS_BANK_CONFLICT == 0). R4 note: LDS-epilogue variant
// REGRESSED (347->381us, +22MB HBM fetch) -- direct scalar epilogue stores
// are absorbed by L2 write-combining; keep them.
// R5 note: 256^2/8-wave/ring-4 counted-vmcnt rewrite REGRESSED (346->446us,
// MfmaUtil 24.6->14.8%): 1 block/CU killed the m114 inter-block overlap and
// the coarse 1-phase-per-K-tile schedule stalled whole-CU at every barrier.
// This 2-barrier 128^2 structure with 3-5 blocks/CU is the verified optimum
// short of the exact 8-phase template ledger. Do not re-attempt custom deep
// pipelines without a verifiable half-tile vmcnt ledger.
// ---------------------------------------------------------------------------
__device__ __forceinline__ void gemm_core(
    const short* __restrict__ Abase, size_t sA,
    const short* __restrict__ Bbase, size_t sB,
    int K,
    short* At, short* Bt,              // 128*64 shorts each (16KB)
    floatx4 acc[4][4])
{
    const int tid  = threadIdx.x;
    const int lane = tid & 63;
    const int wv   = tid >> 6;
    const int lm   = lane & 15, lq = lane >> 4;
    const int rl   = lane >> 3, sl = lane & 7;
    const int usw  = sl ^ rl;                   // swizzled source unit
    const int wm   = (wv & 1) * 64, wn = (wv >> 1) * 64;

    const short* ag = Abase + (size_t)(wv * 32 + rl) * sA + usw * 8;
    const short* bg = Bbase + (size_t)(wv * 32 + rl) * sB + usw * 8;
    short* al = At + wv * 4 * 512;
    short* bl = Bt + wv * 4 * 512;
    const size_t askip = 8 * sA, bskip = 8 * sB;

    for (int kt = 0; kt < K; kt += 64) {
#pragma unroll
        for (int c = 0; c < 4; ++c) glds16(ag + c * askip + kt, al + c * 512);
#pragma unroll
        for (int c = 0; c < 4; ++c) glds16(bg + c * bskip + kt, bl + c * 512);
        __syncthreads();

#pragma unroll
        for (int s = 0; s < 2; ++s) {
            const int u = s * 4 + lq;
            short8 af[4], bf[4];
#pragma unroll
            for (int i = 0; i < 4; ++i) {
                int r = wm + i * 16 + lm;
                af[i] = *(const short8*)&At[((r >> 3) * 64 + (r & 7) * 8 + (u ^ (r & 7))) * 8];
            }
#pragma unroll
            for (int j = 0; j < 4; ++j) {
                int r = wn + j * 16 + lm;
                bf[j] = *(const short8*)&Bt[((r >> 3) * 64 + (r & 7) * 8 + (u ^ (r & 7))) * 8];
            }
#pragma unroll
            for (int i = 0; i < 4; ++i)
#pragma unroll
                for (int j = 0; j < 4; ++j)
                    acc[i][j] = mfma16(af[i], bf[j], acc[i][j]);
        }
        __syncthreads();
    }
}

// ---------------------------------------------------------------------------
// prep: fused front-end (one dispatch replaces convert_wts + q-convert +
// mask_scan + rowsum memset). Flat grid partitioned by block ranges:
//   [0,2304):     weight fp32->bf16 (z = blk/576; Wq scaled by 1/E)
//   [2304,6400):  query fp32->bf16, 4 rows/block
//   [6400,6416):  rowsum zero (16 blocks x 4KB)
//   [6416,6424):  per-batch mask compaction -> jidx, nv, nvp
// ---------------------------------------------------------------------------
__global__ void prep(const float* __restrict__ Wv, const float* __restrict__ Wk,
                     const float* __restrict__ Wq, const float* __restrict__ Wo,
                     const float* __restrict__ query, const int* __restrict__ mask,
                     short* __restrict__ Wb, short* __restrict__ xq,
                     float* __restrict__ rowsum,
                     int* __restrict__ jidx, int* __restrict__ nv,
                     int* __restrict__ nvp)
{
    __shared__ int cnt[256];
    const int blk = blockIdx.x;
    const int t   = threadIdx.x;

    if (blk < 2304) {                       // ---- weight convert
        const int z = blk / 576;
        const float* src = (z == 0) ? Wv : (z == 1) ? Wk : (z == 2) ? Wq : Wo;
        const float scale = (z == 2) ? (1.0f / (float)E_DIM) : 1.0f;
        size_t i = ((size_t)(blk - z * 576) * 256 + t) * 4;
        float4 f = *(const float4*)(src + i);
        short4 h;
        h.x = f2bf(f.x * scale); h.y = f2bf(f.y * scale);
        h.z = f2bf(f.z * scale); h.w = f2bf(f.w * scale);
        *(short4*)(Wb + (size_t)z * E_DIM * E_DIM + i) = h;
    } else if (blk < 6400) {                // ---- query convert, 4 rows/block
        const int g0 = blk - 2304;          // 0..4095
        const size_t base = (size_t)g0 * 4 * E_DIM;   // rows are contiguous over b
#pragma unroll
        for (int p = 0; p < 3; ++p) {
            size_t i = base + ((size_t)p * 256 + t) * 4;
            float4 f = *(const float4*)(query + i);
            short4 h;
            h.x = f2bf(f.x); h.y = f2bf(f.y); h.z = f2bf(f.z); h.w = f2bf(f.w);
            *(short4*)(xq + i) = h;
        }
    } else if (blk < 6416) {                // ---- rowsum zero
        const int g0 = blk - 6400;
        *(float4*)(rowsum + ((size_t)g0 * 256 + t) * 4) = (float4){0.f, 0.f, 0.f, 0.f};
    } else {                                // ---- mask compaction
        const int b = blk - 6416;
        int m[8];
        int c = 0;
#pragma unroll
        for (int k = 0; k < 8; ++k) {
            m[k] = mask[b * S_LEN + t * 8 + k];
            c += (m[k] != 0);
        }
        cnt[t] = c;
        __syncthreads();
        for (int off = 1; off < 256; off <<= 1) {
            int v = (t >= off) ? cnt[t - off] : 0;
            __syncthreads();
            cnt[t] += v;
            __syncthreads();
        }
        int pos = cnt[t] - c;
        const int total = cnt[255];
#pragma unroll
        for (int k = 0; k < 8; ++k)
            if (m[k] != 0) jidx[b * S_LEN + (pos++)] = t * 8 + k;
        __syncthreads();
        for (int i = total + t; i < S_LEN; i += 256) jidx[b * S_LEN + i] = 0;
        if (t == 0) {
            nv[b] = total;
            int p = (total + 127) & ~127;
            if (p < 128) p = 128;
            nvp[b] = p;
        }
    }
}

// ---------------------------------------------------------------------------
// gather+convert value/key rows through jidx (compacted). 4 rows/block.
// ---------------------------------------------------------------------------
__global__ void gather_vk(const float* __restrict__ v, const float* __restrict__ k,
                          const int* __restrict__ jidx, const int* __restrict__ nvp,
                          short* __restrict__ xv, short* __restrict__ xk) {
    const int z = blockIdx.y, b = blockIdx.z;
    const int r0 = blockIdx.x * 4;
    if (r0 >= nvp[b]) return;
    const float* src = (z == 0) ? v : k;
    short* dst = (z == 0) ? xv : xk;
    const int tid = threadIdx.x;
#pragma unroll
    for (int p = 0; p < 3; ++p) {
        int g   = p * 256 + tid;
        int row = r0 + g / 192;
        int c4  = (g % 192) * 4;
        int srow = jidx[b * S_LEN + row];
        float4 f = *(const float4*)(src + ((size_t)b * S_LEN + srow) * E_DIM + c4);
        short4 h;
        h.x = f2bf(f.x); h.y = f2bf(f.y); h.z = f2bf(f.z); h.w = f2bf(f.w);
        *(short4*)(dst + ((size_t)b * S_LEN + row) * E_DIM + c4) = h;
    }
}

// ---------------------------------------------------------------------------
// Projections (m-tiles fast in grid -> W tile shared in L2).
// z==0: V compacted -> vt[b][n][i] (transposed); z==1: K compacted; z==2: Q.
// ---------------------------------------------------------------------------
__global__ __launch_bounds__(256, 3) void proj_kernel(
    const short* __restrict__ xv, const short* __restrict__ xk, const short* __restrict__ xq,
    const short* __restrict__ Wb, const int* __restrict__ nvp,
    short* __restrict__ vt, short* __restrict__ kb, short* __restrict__ qb)
{
    const int z  = blockIdx.z;
    const int mt = blockIdx.x;
    const int n0 = blockIdx.y * 128;

    int b = 0, lm0 = 0;
    const short* X;
    if (z == 2) {
        X = xq + (size_t)mt * 128 * E_DIM;
    } else {
        b   = mt >> 4;
        lm0 = (mt & 15) * 128;
        if (lm0 >= nvp[b]) return;
        X = ((z == 0) ? xv : xk) + ((size_t)b * S_LEN + lm0) * E_DIM;
    }
    const short* W = Wb + (size_t)z * E_DIM * E_DIM + (size_t)n0 * E_DIM;

    __shared__ short At[128 * 64];
    __shared__ short Bt[128 * 64];

    floatx4 acc[4][4];
#pragma unroll
    for (int i = 0; i < 4; ++i)
#pragma unroll
        for (int j = 0; j < 4; ++j) acc[i][j] = (floatx4){0.f, 0.f, 0.f, 0.f};

    gemm_core(X, E_DIM, W, E_DIM, E_DIM, At, Bt, acc);

    const int lane = threadIdx.x & 63, wv = threadIdx.x >> 6;
    const int lm = lane & 15, lq = lane >> 4;
    const int wm = (wv & 1) * 64, wn = (wv >> 1) * 64;

    if (z == 0) {        // vt[b][n][i]
#pragma unroll
        for (int i = 0; i < 4; ++i)
#pragma unroll
            for (int r = 0; r < 4; ++r) {
                int li = lm0 + wm + i * 16 + lq * 4 + r;
#pragma unroll
                for (int j = 0; j < 4; ++j) {
                    int n = n0 + wn + j * 16 + lm;
                    vt[((size_t)b * E_DIM + n) * S_LEN + li] = f2bf(acc[i][j][r]);
                }
            }
    } else if (z == 1) { // kb[b][i][e]
#pragma unroll
        for (int i = 0; i < 4; ++i)
#pragma unroll
            for (int r = 0; r < 4; ++r) {
                int li = lm0 + wm + i * 16 + lq * 4 + r;
#pragma unroll
                for (int j = 0; j < 4; ++j) {
                    int n = n0 + wn + j * 16 + lm;
                    kb[((size_t)b * S_LEN + li) * E_DIM + n] = f2bf(acc[i][j][r]);
                }
            }
    } else {             // qb[m][e]
#pragma unroll
        for (int i = 0; i < 4; ++i)
#pragma unroll
            for (int r = 0; r < 4; ++r) {
                int m = mt * 128 + wm + i * 16 + lq * 4 + r;
#pragma unroll
                for (int j = 0; j < 4; ++j) {
                    int n = n0 + wn + j * 16 + lm;
                    qb[(size_t)m * E_DIM + n] = f2bf(acc[i][j][r]);
                }
            }
    }
}

// ---------------------------------------------------------------------------
// S = q.k^T over compacted columns; fused exp (no max: |s|<0.5) + rowsum.
// ---------------------------------------------------------------------------
__global__ __launch_bounds__(256, 3) void score_kernel(
    const short* __restrict__ qb, const short* __restrict__ kb,
    const int* __restrict__ nv, const int* __restrict__ nvp,
    short* __restrict__ P, float* __restrict__ rowsum)
{
    const int b  = blockIdx.z;
    const int m0 = blockIdx.x * 128;
    const int n0 = blockIdx.y * 128;
    if (n0 >= nvp[b]) return;

    __shared__ short At[128 * 64];
    __shared__ short Bt[128 * 64];

    floatx4 acc[4][4];
#pragma unroll
    for (int i = 0; i < 4; ++i)
#pragma unroll
        for (int j = 0; j < 4; ++j) acc[i][j] = (floatx4){0.f, 0.f, 0.f, 0.f};

    gemm_core(qb + ((size_t)b * S_LEN + m0) * E_DIM, E_DIM,
              kb + ((size_t)b * S_LEN + n0) * E_DIM, E_DIM, E_DIM, At, Bt, acc);

    const int lane = threadIdx.x & 63, wv = threadIdx.x >> 6;
    const int lm = lane & 15, lq = lane >> 4;
    const int wm = (wv & 1) * 64, wn = (wv >> 1) * 64;
    const int nvb = nv[b];

    float rsum[4][4];
#pragma unroll
    for (int i = 0; i < 4; ++i)
#pragma unroll
        for (int r = 0; r < 4; ++r) rsum[i][r] = 0.f;

    const size_t Pbb = (size_t)b * S_LEN * S_LEN;
#pragma unroll
    for (int j = 0; j < 4; ++j) {
        int n = n0 + wn + j * 16 + lm;
        bool valid = n < nvb;
#pragma unroll
        for (int i = 0; i < 4; ++i) {
            int mbase = m0 + wm + i * 16 + lq * 4;
#pragma unroll
            for (int r = 0; r < 4; ++r) {
                float p = valid ? __expf(acc[i][j][r]) : 0.0f;
                rsum[i][r] += p;
                P[Pbb + (size_t)(mbase + r) * S_LEN + n] = f2bf(p);
            }
        }
    }
#pragma unroll
    for (int i = 0; i < 4; ++i)
#pragma unroll
        for (int r = 0; r < 4; ++r) {
            float v = rsum[i][r];
            v += __shfl_xor(v, 1);
            v += __shfl_xor(v, 2);
            v += __shfl_xor(v, 4);
            v += __shfl_xor(v, 8);
            if (lm == 0)
                atomicAdd(&rowsum[b * S_LEN + m0 + wm + i * 16 + lq * 4 + r], v);
        }
}

// ---------------------------------------------------------------------------
// O = (P.V)/rowsum over compacted K (nvp[b]) -> abuf bf16.
// ---------------------------------------------------------------------------
__global__ __launch_bounds__(256, 3) void pv_kernel(
    const short* __restrict__ P, const short* __restrict__ vt,
    const float* __restrict__ rowsum, const int* __restrict__ nvp,
    short* __restrict__ abuf)
{
    const int b  = blockIdx.z;
    const int m0 = blockIdx.x * 128;
    const int n0 = blockIdx.y * 128;

    __shared__ short At[128 * 64];
    __shared__ short Bt[128 * 64];

    floatx4 acc[4][4];
#pragma unroll
    for (int i = 0; i < 4; ++i)
#pragma unroll
        for (int j = 0; j < 4; ++j) acc[i][j] = (floatx4){0.f, 0.f, 0.f, 0.f};

    gemm_core(P + (size_t)b * S_LEN * S_LEN + (size_t)m0 * S_LEN, S_LEN,
              vt + ((size_t)b * E_DIM + n0) * S_LEN, S_LEN, nvp[b], At, Bt, acc);

    const int lane = threadIdx.x & 63, wv = threadIdx.x >> 6;
    const int lm = lane & 15, lq = lane >> 4;
    const int wm = (wv & 1) * 64, wn = (wv >> 1) * 64;

#pragma unroll
    for (int i = 0; i < 4; ++i) {
        int mbase = m0 + wm + i * 16 + lq * 4;
#pragma unroll
        for (int r = 0; r < 4; ++r) {
            float inv = 1.0f / rowsum[b * S_LEN + mbase + r];
            size_t ob = ((size_t)b * S_LEN + mbase + r) * E_DIM;
#pragma unroll
            for (int j = 0; j < 4; ++j) {
                int n = n0 + wn + j * 16 + lm;
                abuf[ob + n] = f2bf(acc[i][j][r] * inv);
            }
        }
    }
}

// ---------------------------------------------------------------------------
// out[m,n] = A[m,:].Wo[n,:] + bo[n]  (fp32 out). m-fast grid.
// ---------------------------------------------------------------------------
__global__ __launch_bounds__(256, 3) void out_kernel(
    const short* __restrict__ A, const short* __restrict__ W,
    const float* __restrict__ bias, float* __restrict__ Y)
{
    const int m0 = blockIdx.x * 128;
    const int n0 = blockIdx.y * 128;

    __shared__ short At[128 * 64];
    __shared__ short Bt[128 * 64];

    floatx4 acc[4][4];
#pragma unroll
    for (int i = 0; i < 4; ++i)
#pragma unroll
        for (int j = 0; j < 4; ++j) acc[i][j] = (floatx4){0.f, 0.f, 0.f, 0.f};

    gemm_core(A + (size_t)m0 * E_DIM, E_DIM, W + (size_t)n0 * E_DIM, E_DIM,
              E_DIM, At, Bt, acc);

    const int lane = threadIdx.x & 63, wv = threadIdx.x >> 6;
    const int lm = lane & 15, lq = lane >> 4;
    const int wm = (wv & 1) * 64, wn = (wv >> 1) * 64;

#pragma unroll
    for (int j = 0; j < 4; ++j) {
        int n = n0 + wn + j * 16 + lm;
        float bv = bias[n];
#pragma unroll
        for (int i = 0; i < 4; ++i)
#pragma unroll
            for (int r = 0; r < 4; ++r) {
                int m = m0 + wm + i * 16 + lq * 4 + r;
                Y[(size_t)m * E_DIM + n] = acc[i][j][r] + bv;
            }
    }
}

// ---------------------------------------------------------------------------
extern "C" void kernel_launch(void* const* d_in, const int* in_sizes, int n_in,
                              void* d_out, int out_size, void* d_ws, size_t ws_size,
                              hipStream_t stream) {
    const float* value = (const float*)d_in[0];
    const float* key   = (const float*)d_in[1];
    const float* query = (const float*)d_in[2];
    const int*   mask  = (const int*)d_in[3];
    const float* Wv    = (const float*)d_in[4];
    const float* Wk    = (const float*)d_in[5];
    const float* Wq    = (const float*)d_in[6];
    const float* Wo    = (const float*)d_in[7];
    const float* bo    = (const float*)d_in[8];
    float* out = (float*)d_out;

    const size_t WN  = (size_t)E_DIM * E_DIM;
    const size_t ACT = (size_t)BATCH * S_LEN * E_DIM;

    short* Wb  = (short*)d_ws;
    short* xv  = Wb + 4 * WN;
    short* xk  = xv + ACT;
    short* xq  = xk + ACT;
    short* vt  = xq + ACT;
    short* kb  = vt + ACT;
    short* qb  = kb + ACT;
    float* rowsum = (float*)(qb + ACT);
    int*   nv  = (int*)(rowsum + (size_t)BATCH * S_LEN);
    int*   nvp = nv + BATCH;
    int*   jidx = (int*)qb;            // consumed by gather before proj writes qb
    short* P    = xv;                  // overlays dead xv/xk
    short* abuf = qb;                  // overlays dead qb

    // 6 dispatches total (was 9): prep fuses wconv+qconv+mask_scan+memset.
    prep<<<6424, 256, 0, stream>>>(Wv, Wk, Wq, Wo, query, mask,
                                   Wb, xq, rowsum, jidx, nv, nvp);

    gather_vk<<<dim3(512, 2, 8), 256, 0, stream>>>(value, key, jidx, nvp, xv, xk);

    proj_kernel<<<dim3(128, 6, 3), 256, 0, stream>>>(xv, xk, xq, Wb, nvp,
                                                     vt, kb, qb);

    score_kernel<<<dim3(16, 16, 8), 256, 0, stream>>>(qb, kb, nv, nvp, P, rowsum);

    pv_kernel<<<dim3(16, 6, 8), 256, 0, stream>>>(P, vt, rowsum, nvp, abuf);

    out_kernel<<<dim3(128, 6), 256, 0, stream>>>(abuf, Wb + 3 * WN, bo, out);
}